// Round 4
// baseline (551.564 us; speedup 1.0000x reference)
//
#include <hip/hip_runtime.h>
#include <math.h>

// AugmentPipe: flip -> affine(rot/scale/trans) bilinear-reflect sample ->
// brightness -> contrast -> saturation -> cutout(noise). One fused pass.
// B=64, C=3, H=W=512, float32 in/out.
//
// R5 -> R6 (R5: 182us; VALU 50%, HBM 25%, DS ~20%, nothing saturated =>
// phase-serialized convoy: per-block load->drain->write->barrier->compute).
// Changes:
//   (1) PERSISTENT blocks: each block = one 512-wide tile-row (32 tiles of
//       16x16) of one batch. Double-buffered LDS pipeline: compute tile t
//       from buf[t&1] while writing tile t+1 (prefetched into regs one full
//       phase earlier) to buf[~t&1] and issuing loads for tile t+2.
//   (2) ONE barrier/tile: asm lgkmcnt(0) + raw s_barrier + sched_barrier(0).
//       No vmcnt drain => prefetch loads stay in flight across the barrier
//       (plain __syncthreads emits vmcnt(0) and would re-serialize).
//       Race-free: reads(t) are data-consumed before each wave reaches
//       barrier(t); writes into that buffer only occur after barrier(t).
//   (3) Incremental affine coords (xx = org + px*dxdx + py*dxdy): 4 fma/px.
//       Output is continuous in (xx,yy) (bilinear, reflect, clips), so the
//       ~1e-3 px fp difference vs the reference chain is ~2e-4 in values.
//   (4) FSTRIDE 41 (odd): row bank-parity alternates -> 2-way max on gather
//       and staging (R5's stride 40 left 6.1M conflict cycles).
//   (5) bid -> (xcd, batch, row): batch = (bid&7)*8 + ..., so one batch
//       (3MB) lives in one XCD's 4MB L2; tile-row staggered by 13*batch so
//       edge-row (fallback-heavy) blocks spread across CUs.

constexpr int Bn = 64;
constexpr int Cn = 3;
constexpr int Hn = 512;
constexpr int Wn = 512;
constexpr float TRANSLATE_STD = 0.125f;
constexpr float SCALE_STD = 0.2f;
constexpr int CUT_H = 256; // int(512*0.5)
constexpr int CUT_W = 256;

constexpr int FW = 32;       // staged box width
constexpr int FSTRIDE = 41;  // odd stride: conflict-free in both rotations
constexpr int FH_MAX = 32;   // staged rows capacity (math bound 30)
constexpr int CH_LDS = FSTRIDE * FH_MAX;   // 1312 floats per channel
constexpr int BUF_LDS = Cn * CH_LDS;       // one pipeline buffer
constexpr int NT = 32;       // tiles per block (one tile-row)

typedef float f2v __attribute__((ext_vector_type(2)));

__device__ __forceinline__ f2v load2(const float* p) {
    f2v r;
    __builtin_memcpy(&r, p, 8);
    return r;
}

__device__ __forceinline__ float reflect_coord(float v, float size) {
    v = fabsf(v + 0.5f);
    v = fmodf(v, 2.0f * size);
    v = fminf(v, 2.0f * size - v);
    return fminf(fmaxf(v - 0.5f, 0.0f), size - 1.0f);
}

// Pipeline barrier: DS ops drained & visible; VMEM prefetch stays in flight.
__device__ __forceinline__ void pipe_barrier() {
    asm volatile("s_waitcnt lgkmcnt(0)" ::: "memory");
    __builtin_amdgcn_s_barrier();
    __builtin_amdgcn_sched_barrier(0);
}

__global__ __launch_bounds__(256) void augment_kernel(
    const float* __restrict__ images,
    const float* __restrict__ u_angle,
    const float* __restrict__ u_scale,
    const float* __restrict__ u_trans,
    const float* __restrict__ u_bright,
    const float* __restrict__ u_contrast,
    const float* __restrict__ u_sat,
    const float* __restrict__ noise,
    const int* __restrict__ m_flip,
    const int* __restrict__ m_rot,
    const int* __restrict__ m_scale,
    const int* __restrict__ m_trans,
    const int* __restrict__ m_bright,
    const int* __restrict__ m_contrast,
    const int* __restrict__ m_sat,
    const int* __restrict__ m_cut,
    const int* __restrict__ y0p,
    const int* __restrict__ x0p,
    float* __restrict__ out)
{
    __shared__ __align__(16) float lds[2 * BUF_LDS];   // 31488 B -> 5 blk/CU

    // bid -> (xcd, local batch, staggered tile-row)
    const int bid = blockIdx.x;
    const int jj  = bid >> 3;                 // 0..255 within XCD
    const int lb  = jj >> 5;                  // 0..7 local batch
    const int b   = (bid & 7) * 8 + lb;       // batch, XCD-resident
    const int trow = ((jj & 31) + lb * 13) & 31;

    const int tx  = threadIdx.x;
    const int tyy = threadIdx.y;
    const int y   = trow * 16 + tyy;

    // Per-batch params — uniform per block.
    const float angle = (m_rot[b] > 0) ? (u_angle[b] * 2.0f - 1.0f) * 3.14159265358979323846f : 0.0f;
    const float sc    = (m_scale[b] > 0) ? (u_scale[b] * 2.0f - 1.0f) * SCALE_STD + 1.0f : 1.0f;
    const float tr    = (m_trans[b] > 0) ? (u_trans[b] * 2.0f - 1.0f) * TRANSLATE_STD : 0.0f;
    const float bb    = (m_bright[b] > 0) ? u_bright[b] * 0.2f : 0.0f;
    const float cc    = (m_contrast[b] > 0) ? u_contrast[b] + 0.5f : 1.0f;
    const float ss    = (m_sat[b] > 0) ? u_sat[b] * 2.0f : 1.0f;
    const bool  flip  = m_flip[b] > 0;
    const bool  docut = m_cut[b] > 0;
    const int   cy0   = y0p[b];
    const int   cx0   = x0p[b];

    float saf, caf;
    __sincosf(angle, &saf, &caf);

    // Incremental affine basis: xx(px,py) = xx_org + px*dxdx + py*dxdy.
    const float kk = sc * (512.0f / 511.0f);
    const float dxdx = caf * kk, dxdy = -saf * kk;
    const float dydx = saf * kk, dydy = caf * kk;
    const float xx_org = 256.0f * (sc * (saf - caf) + tr + 1.0f) - 0.5f;
    const float yy_org = 256.0f * (sc * (-saf - caf) + tr + 1.0f) - 0.5f;

    const float tstep_x = 16.0f * dxdx;       // per-tile coordinate step
    const float tstep_y = 16.0f * dydx;

    float xxt = xx_org + (float)tx * dxdx + (float)y * dxdy;   // tile 0
    float yyt = yy_org + (float)tx * dydx + (float)y * dydy;

    // Tile-corner rolling values + span extrema for the bbox.
    const float fty = (float)(trow * 16);
    const float bx0 = xx_org + fty * dxdy;
    const float by0 = yy_org + fty * dydy;
    const float sxx = 15.0f * dxdx, sxy = 15.0f * dxdy;
    const float syx = 15.0f * dydx, syy = 15.0f * dydy;
    const float min_dx = fminf(sxx, 0.0f) + fminf(sxy, 0.0f);
    const float max_dx = fmaxf(sxx, 0.0f) + fmaxf(sxy, 0.0f);
    const float min_dy = fminf(syx, 0.0f) + fminf(syy, 0.0f);
    const float max_dy = fmaxf(syx, 0.0f) + fmaxf(syy, 0.0f);

    const size_t plane = (size_t)Hn * Wn;
    const float* imgb = images + (size_t)b * Cn * plane;

    // Staging lane geometry (constant across tiles).
    const int tid = tyy * 16 + tx;
    const int k2  = (tid & 15) * 2;           // pair column 0..30
    const int sry = tid >> 4;                 // row 0..15
    const size_t srow = (size_t)sry * Wn;

    const bool ycut = docut && (y >= cy0) && (y < cy0 + CUT_H);
    const size_t obase = (size_t)b * Cn * plane + (size_t)y * Wn;

    // Interior box: reflect==clip holds and taps never clamp (gate as in
    // harness-passed R5: [1, 509] with +-1px box slack).
    auto mkbox = [&](float bxt, float byt, int& x_lo, int& y_lo, int& fh, bool& ok) {
        const float minxx = bxt + min_dx, maxxx = bxt + max_dx;
        const float minyy = byt + min_dy, maxyy = byt + max_dy;
        ok = (minxx >= 1.0f) && (maxxx <= 509.0f) &&
             (minyy >= 1.0f) && (maxyy <= 509.0f);
        x_lo = 0; y_lo = 0; fh = 0;
        if (ok) {
            x_lo = min((int)minxx - 1, Wn - FW);
            y_lo = (int)minyy - 1;
            fh   = ((int)maxyy + 2) - y_lo + 1;   // <= 30 by math
            if (fh > FH_MAX) ok = false;          // safety
        }
    };

    // Prefetch registers (tile t+1's staged data).
    f2v a0{}, b0{}, c0{}, a1{}, b1{}, c1{};

    auto issueR = [&](int x_lo, int y_lo, int fh) {
        const int scol = flip ? (Wn - 2 - (x_lo + k2)) : (x_lo + k2);
        const float* sp = imgb + (size_t)y_lo * Wn + srow + scol;
        if (sry < fh) {
            a0 = load2(sp);
            b0 = load2(sp + plane);
            c0 = load2(sp + 2 * plane);
        }
        if (sry + 16 < fh) {
            const float* sp2 = sp + 16 * Wn;
            a1 = load2(sp2);
            b1 = load2(sp2 + plane);
            c1 = load2(sp2 + 2 * plane);
        }
    };

    auto writeR = [&](float* buf, int fh) {
        float* d = buf + sry * FSTRIDE + k2;
        if (sry < fh) {
            if (flip) {
                d[0] = a0.y; d[1] = a0.x;
                d[CH_LDS] = b0.y; d[CH_LDS + 1] = b0.x;
                d[2 * CH_LDS] = c0.y; d[2 * CH_LDS + 1] = c0.x;
            } else {
                d[0] = a0.x; d[1] = a0.y;
                d[CH_LDS] = b0.x; d[CH_LDS + 1] = b0.y;
                d[2 * CH_LDS] = c0.x; d[2 * CH_LDS + 1] = c0.y;
            }
        }
        if (sry + 16 < fh) {
            float* d2 = d + 16 * FSTRIDE;
            if (flip) {
                d2[0] = a1.y; d2[1] = a1.x;
                d2[CH_LDS] = b1.y; d2[CH_LDS + 1] = b1.x;
                d2[2 * CH_LDS] = c1.y; d2[2 * CH_LDS + 1] = c1.x;
            } else {
                d2[0] = a1.x; d2[1] = a1.y;
                d2[CH_LDS] = b1.x; d2[CH_LDS + 1] = b1.y;
                d2[2 * CH_LDS] = c1.x; d2[2 * CH_LDS + 1] = c1.y;
            }
        }
    };

    // ---- Pipeline prologue: tile0 staged to buf0; tile1 loads in flight.
    int cx_lo, cy_lo, cfh; bool cok;
    int nx_lo, ny_lo, nfh; bool nok;

    mkbox(bx0, by0, cx_lo, cy_lo, cfh, cok);
    if (cok) { issueR(cx_lo, cy_lo, cfh); writeR(lds, cfh); }  // vmcnt auto
    mkbox(bx0 + tstep_x, by0 + tstep_y, nx_lo, ny_lo, nfh, nok);
    if (nok) issueR(nx_lo, ny_lo, nfh);
    float bxn = bx0 + 2.0f * tstep_x;
    float byn = by0 + 2.0f * tstep_y;
    pipe_barrier();

    #pragma unroll 1
    for (int t = 0; t < NT; ++t) {
        float vals[Cn];

        if (cok) {
            // ---- Exact bilinear from LDS buf[t&1]; no clamps (interior).
            const float* buf = lds + (t & 1) * BUF_LDS;
            const float fx = xxt - (float)cx_lo;
            const float fy = yyt - (float)cy_lo;
            const int xi = (int)fx;
            const int yi = (int)fy;
            const float wx = fx - (float)xi;
            const float wy = fy - (float)yi;
            const float* ph = buf + yi * FSTRIDE + xi;
            #pragma unroll
            for (int c = 0; c < Cn; ++c) {
                const float v00 = ph[0], v01 = ph[1];
                const float v10 = ph[FSTRIDE], v11 = ph[FSTRIDE + 1];
                ph += CH_LDS;
                const float top = v00 + wx * (v01 - v00);
                const float bot = v10 + wx * (v11 - v10);
                float v = top + wy * (bot - top);
                v = fminf(fmaxf(v + bb, -1.0f), 1.0f);   // brightness + clip
                v = fminf(fmaxf(v * cc, -1.0f), 1.0f);   // contrast + clip
                vals[c] = v;
            }
        } else {
            // ---- Edge/reflecting tiles: direct global gather, true reflect.
            const float rxx = reflect_coord(xxt, (float)Wn);
            const float ryy = reflect_coord(yyt, (float)Hn);
            const float x0f = floorf(rxx);
            const float y0f = floorf(ryy);
            const float wx = rxx - x0f;
            const float wy = ryy - y0f;
            int x0i = (int)fminf(fmaxf(x0f, 0.0f), (float)(Wn - 1));
            int x1i = (int)fminf(x0f + 1.0f, (float)(Wn - 1));
            const int y0i = (int)fminf(fmaxf(y0f, 0.0f), (float)(Hn - 1));
            const int y1i = (int)fminf(y0f + 1.0f, (float)(Hn - 1));
            if (flip) { x0i = (Wn - 1) - x0i; x1i = (Wn - 1) - x1i; }
            const int xbase = min(min(x0i, x1i), Wn - 2);
            const bool s0 = (x0i != xbase);
            const bool s1 = (x1i != xbase);
            const int r0 = y0i * Wn + xbase;
            const int r1 = y1i * Wn + xbase;
            #pragma unroll
            for (int c = 0; c < Cn; ++c) {
                const float* p = imgb + (size_t)c * plane;
                const f2v t0 = load2(p + r0);
                const f2v t1 = load2(p + r1);
                const float v00 = s0 ? t0.y : t0.x;
                const float v01 = s1 ? t0.y : t0.x;
                const float v10 = s0 ? t1.y : t1.x;
                const float v11 = s1 ? t1.y : t1.x;
                const float top = v00 + wx * (v01 - v00);
                const float bot = v10 + wx * (v11 - v10);
                float v = top + wy * (bot - top);
                v = fminf(fmaxf(v + bb, -1.0f), 1.0f);
                v = fminf(fmaxf(v * cc, -1.0f), 1.0f);
                vals[c] = v;
            }
        }

        // ---- Saturation + cutout + store for tile t.
        const int x = (t << 4) + tx;
        const float gray = (vals[0] + vals[1] + vals[2]) * (1.0f / 3.0f);
        const bool cut = ycut && (x >= cx0) && (x < cx0 + CUT_W);
        const size_t base = obase + (size_t)x;
        #pragma unroll
        for (int c = 0; c < Cn; ++c) {
            float v = gray + ss * (vals[c] - gray);
            v = fminf(fmaxf(v, -1.0f), 1.0f);
            if (cut) v = __builtin_nontemporal_load(&noise[base + c * plane]);
            __builtin_nontemporal_store(v, &out[base + c * plane]);
        }

        // ---- Stage tile t+1 into the other buffer (waits on its loads,
        // issued one full compute phase ago), then issue tile t+2's loads.
        float* wbuf = lds + ((t & 1) ^ 1) * BUF_LDS;
        if (nok) writeR(wbuf, nfh);

        cx_lo = nx_lo; cy_lo = ny_lo; cfh = nfh; cok = nok;
        if (t + 2 < NT) {
            mkbox(bxn, byn, nx_lo, ny_lo, nfh, nok);
            if (nok) issueR(nx_lo, ny_lo, nfh);
        } else {
            nok = false;
        }
        bxn += tstep_x; byn += tstep_y;
        xxt += tstep_x; yyt += tstep_y;

        pipe_barrier();
    }
}

extern "C" void kernel_launch(void* const* d_in, const int* in_sizes, int n_in,
                              void* d_out, int out_size, void* d_ws, size_t ws_size,
                              hipStream_t stream) {
    const float* images     = (const float*)d_in[0];
    const float* u_angle    = (const float*)d_in[1];
    const float* u_scale    = (const float*)d_in[2];
    const float* u_trans    = (const float*)d_in[3];
    const float* u_bright   = (const float*)d_in[4];
    const float* u_contrast = (const float*)d_in[5];
    const float* u_sat      = (const float*)d_in[6];
    const float* noise      = (const float*)d_in[7];
    const int*   m_flip     = (const int*)d_in[8];
    const int*   m_rot      = (const int*)d_in[9];
    const int*   m_scale    = (const int*)d_in[10];
    const int*   m_trans    = (const int*)d_in[11];
    const int*   m_bright   = (const int*)d_in[12];
    const int*   m_contrast = (const int*)d_in[13];
    const int*   m_sat      = (const int*)d_in[14];
    const int*   m_cut      = (const int*)d_in[15];
    const int*   y0p        = (const int*)d_in[16];
    const int*   x0p        = (const int*)d_in[17];
    float* out = (float*)d_out;

    dim3 block(16, 16);
    dim3 grid(Bn * 32, 1, 1);   // 2048 blocks: one 16-row strip each
    augment_kernel<<<grid, block, 0, stream>>>(
        images, u_angle, u_scale, u_trans, u_bright, u_contrast, u_sat, noise,
        m_flip, m_rot, m_scale, m_trans, m_bright, m_contrast, m_sat, m_cut,
        y0p, x0p, out);
}

// Round 6
// 517.779 us; speedup vs baseline: 1.0652x; 1.0652x over previous
//
#include <hip/hip_runtime.h>
#include <math.h>

// AugmentPipe: flip -> affine(rot/scale/trans) bilinear-reflect sample ->
// brightness -> contrast -> saturation -> cutout(noise). One fused pass.
// B=64, C=3, H=W=512, float32 in/out.
//
// R7 -> R8: R7 failed correctness (absmax 2.0). Root cause: staging writes
// 8 quad-cols x 4 = 32 LDS columns, but FW=36 let the x_lo clamp sit at 476;
// tiles with box right edge in [507,509] needed staged column 32..33 ->
// stale LDS from the previous tile. Fix: FW=32 (clamp 480, still 4-aligned).
// Bounds: unclamped needed col <= span(25.5)+5 = 31; clamped <= 510-480=30.
// Otherwise identical to R7:
//   (1) Block = 128x16 strip = 8 tiles of 16x16; per-batch setup /8, box
//       rolls with 2 adds/tile, incremental affine coords (validated R6).
//   (2) Single 15.4KB LDS buffer, 2 __syncthreads/tile -> 8 blocks/CU.
//   (3) All global accesses = uniform base + 32-bit offset (saddr form).
//   (4) Staging: x_lo 4-aligned; 3x dwordx4 + 3x ds_write_b128 per thread.
//   (5) fmed3 clamps.
//   (6) FSTRIDE 40; residual ~6M conflict cycles are gather-intrinsic.

constexpr int Bn = 64;
constexpr int Cn = 3;
constexpr int Hn = 512;
constexpr int Wn = 512;
constexpr float TRANSLATE_STD = 0.125f;
constexpr float SCALE_STD = 0.2f;
constexpr int CUT_H = 256; // int(512*0.5)
constexpr int CUT_W = 256;

constexpr int FW = 32;        // staged box width == exactly what staging fills
constexpr int FSTRIDE = 40;   // LDS row stride (160B, 16B-aligned rows)
constexpr int FH_MAX = 32;    // staged rows capacity (math bound 30)
constexpr int CH_LDS = FSTRIDE * FH_MAX;   // 1280 floats per channel
constexpr int NT = 8;         // tiles per block (128x16 strip)
constexpr uint32_t PLANE = 512u * 512u;

typedef float f4v __attribute__((ext_vector_type(4)));
typedef float f2v __attribute__((ext_vector_type(2)));

__device__ __forceinline__ f2v load2(const float* p) {
    f2v r;
    __builtin_memcpy(&r, p, 8);
    return r;
}

__device__ __forceinline__ float reflect_coord(float v, float size) {
    v = fabsf(v + 0.5f);
    v = fmodf(v, 2.0f * size);
    v = fminf(v, 2.0f * size - v);
    return fminf(fmaxf(v - 0.5f, 0.0f), size - 1.0f);
}

__global__ __launch_bounds__(256) void augment_kernel(
    const float* __restrict__ images,
    const float* __restrict__ u_angle,
    const float* __restrict__ u_scale,
    const float* __restrict__ u_trans,
    const float* __restrict__ u_bright,
    const float* __restrict__ u_contrast,
    const float* __restrict__ u_sat,
    const float* __restrict__ noise,
    const int* __restrict__ m_flip,
    const int* __restrict__ m_rot,
    const int* __restrict__ m_scale,
    const int* __restrict__ m_trans,
    const int* __restrict__ m_bright,
    const int* __restrict__ m_contrast,
    const int* __restrict__ m_sat,
    const int* __restrict__ m_cut,
    const int* __restrict__ y0p,
    const int* __restrict__ x0p,
    float* __restrict__ out)
{
    __shared__ __align__(16) float lds[Cn * CH_LDS];   // 15360 B -> 8 blk/CU

    const int tx  = threadIdx.x;               // 0..15
    const int ty  = threadIdx.y;               // 0..15
    const int sx0 = blockIdx.x * (16 * NT);    // strip origin x
    const int y   = blockIdx.y * 16 + ty;
    const int b   = blockIdx.z;

    // ---- Per-batch setup (once per thread, amortized over 8 px).
    const float angle = (m_rot[b] > 0) ? (u_angle[b] * 2.0f - 1.0f) * 3.14159265358979323846f : 0.0f;
    const float sc    = (m_scale[b] > 0) ? (u_scale[b] * 2.0f - 1.0f) * SCALE_STD + 1.0f : 1.0f;
    const float tr    = (m_trans[b] > 0) ? (u_trans[b] * 2.0f - 1.0f) * TRANSLATE_STD : 0.0f;
    const float bb    = (m_bright[b] > 0) ? u_bright[b] * 0.2f : 0.0f;
    const float cc    = (m_contrast[b] > 0) ? u_contrast[b] + 0.5f : 1.0f;
    const float ss    = (m_sat[b] > 0) ? u_sat[b] * 2.0f : 1.0f;
    const bool  flip  = m_flip[b] > 0;
    const bool  docut = m_cut[b] > 0;
    const int   cy0   = y0p[b];
    const int   cx0   = x0p[b];

    float saf, caf;
    __sincosf(angle, &saf, &caf);

    // Incremental affine basis (validated in R6: output continuous in
    // (xx,yy), fp drift ~1e-3 px << tolerance and << 1px box slack).
    const float kk = sc * (512.0f / 511.0f);
    const float dxdx = caf * kk, dxdy = -saf * kk;
    const float dydx = saf * kk, dydy = caf * kk;
    const float xx_org = 256.0f * (sc * (saf - caf) + tr + 1.0f) - 0.5f;
    const float yy_org = 256.0f * (sc * (-saf - caf) + tr + 1.0f) - 0.5f;

    const float step_x = 16.0f * dxdx;         // per-tile coordinate step
    const float step_y = 16.0f * dydx;

    float xxt = xx_org + (float)(sx0 + tx) * dxdx + (float)y * dxdy;
    float yyt = yy_org + (float)(sx0 + tx) * dydx + (float)y * dydy;

    // Rolling tile-corner + span extrema for the bbox (affine => exact).
    const float fty = (float)(blockIdx.y * 16);
    float bx = xx_org + (float)sx0 * dxdx + fty * dxdy;
    float by = yy_org + (float)sx0 * dydx + fty * dydy;
    const float sxx = 15.0f * dxdx, sxy = 15.0f * dxdy;
    const float syx = 15.0f * dydx, syy = 15.0f * dydy;
    const float min_dx = fminf(sxx, 0.0f) + fminf(sxy, 0.0f);
    const float max_dx = fmaxf(sxx, 0.0f) + fmaxf(sxy, 0.0f);
    const float min_dy = fminf(syx, 0.0f) + fminf(syy, 0.0f);
    const float max_dy = fmaxf(syx, 0.0f) + fmaxf(syy, 0.0f);

    // Uniform bases (saddr-form accesses; all offsets 32-bit).
    const float* __restrict__ imgb = images + (size_t)b * (Cn * PLANE);
    float* __restrict__ outb       = out    + (size_t)b * (Cn * PLANE);
    const float* __restrict__ noib = noise  + (size_t)b * (Cn * PLANE);

    // Staging lane geometry: 32 rows x 8 quad-columns (= 32 cols = FW).
    const int tid = ty * 16 + tx;
    const int sr  = tid >> 3;            // staged row 0..31
    const int sq  = (tid & 7) << 2;      // quad col offset 0,4,..,28

    const bool ycut = docut && (y >= cy0) && (y < cy0 + CUT_H);
    uint32_t opix = (uint32_t)y * 512u + (uint32_t)(sx0 + tx);

    #pragma unroll 1
    for (int t = 0; t < NT; ++t) {
        // ---- Box for tile t. Interior gate: taps (floor-1..floor+2) inside
        // [0,511] => reflect==clip AND no clamping (same gate as R5/R6).
        const float minxx = bx + min_dx, maxxx = bx + max_dx;
        const float minyy = by + min_dy, maxyy = by + max_dy;
        bool cok = (minxx >= 1.0f) && (maxxx <= 509.0f) &&
                   (minyy >= 1.0f) && (maxyy <= 509.0f);
        int x_lo = 0, y_lo = 0, fh = 0;
        if (cok) {
            x_lo = min(((int)minxx - 1) & ~3, Wn - FW);  // 4-aligned, <=480
            y_lo = (int)minyy - 1;
            fh   = ((int)maxyy + 2) - y_lo + 1;          // <= 30 by math
            if (fh > FH_MAX) cok = false;                // safety
        }

        if (t > 0) __syncthreads();      // all reads of tile t-1 done

        if (cok && sr < fh) {
            // Stage: 3x dwordx4 (16B aligned: x_lo, sq, flip-base all %4==0)
            const int scol = flip ? (508 - x_lo - sq) : (x_lo + sq);
            const uint32_t soff = (uint32_t)(y_lo + sr) * 512u + (uint32_t)scol;
            f4v A = *(const f4v*)(imgb + soff);
            f4v B = *(const f4v*)(imgb + soff + PLANE);
            f4v C = *(const f4v*)(imgb + soff + 2 * PLANE);
            if (flip) {   // reversed quad
                A = f4v{A.w, A.z, A.y, A.x};
                B = f4v{B.w, B.z, B.y, B.x};
                C = f4v{C.w, C.z, C.y, C.x};
            }
            float* d = &lds[sr * FSTRIDE + sq];
            *(f4v*)(d)              = A;
            *(f4v*)(d + CH_LDS)     = B;
            *(f4v*)(d + 2 * CH_LDS) = C;
        }
        __syncthreads();

        float vals[Cn];
        if (cok) {
            // ---- Exact bilinear from LDS: no clamps, no selects.
            const float fx = xxt - (float)x_lo;
            const float fy = yyt - (float)y_lo;
            const int xi = (int)fx;
            const int yi = (int)fy;
            const float wx = fx - (float)xi;
            const float wy = fy - (float)yi;
            const float* ph = &lds[yi * FSTRIDE + xi];
            #pragma unroll
            for (int c = 0; c < Cn; ++c) {
                const float v00 = ph[0], v01 = ph[1];
                const float v10 = ph[FSTRIDE], v11 = ph[FSTRIDE + 1];
                ph += CH_LDS;
                const float top = v00 + wx * (v01 - v00);
                const float bot = v10 + wx * (v11 - v10);
                float v = top + wy * (bot - top);
                v = __builtin_amdgcn_fmed3f(v + bb, -1.0f, 1.0f);  // bright
                v = __builtin_amdgcn_fmed3f(v * cc, -1.0f, 1.0f);  // contrast
                vals[c] = v;
            }
        } else {
            // ---- Edge/reflecting tiles: direct global gather, true reflect
            // (identical math to harness-passed R2/R5 fallback).
            const float rxx = reflect_coord(xxt, (float)Wn);
            const float ryy = reflect_coord(yyt, (float)Hn);
            const float x0f = floorf(rxx);
            const float y0f = floorf(ryy);
            const float wx = rxx - x0f;
            const float wy = ryy - y0f;
            int x0i = (int)fminf(fmaxf(x0f, 0.0f), 511.0f);
            int x1i = (int)fminf(x0f + 1.0f, 511.0f);
            const int y0i = (int)fminf(fmaxf(y0f, 0.0f), 511.0f);
            const int y1i = (int)fminf(y0f + 1.0f, 511.0f);
            if (flip) { x0i = 511 - x0i; x1i = 511 - x1i; }
            const int xbase = min(min(x0i, x1i), 510);
            const bool s0 = (x0i != xbase);
            const bool s1 = (x1i != xbase);
            const uint32_t r0 = (uint32_t)(y0i * 512 + xbase);
            const uint32_t r1 = (uint32_t)(y1i * 512 + xbase);
            #pragma unroll
            for (int c = 0; c < Cn; ++c) {
                const f2v t0 = load2(imgb + r0 + c * PLANE);
                const f2v t1 = load2(imgb + r1 + c * PLANE);
                const float v00 = s0 ? t0.y : t0.x;
                const float v01 = s1 ? t0.y : t0.x;
                const float v10 = s0 ? t1.y : t1.x;
                const float v11 = s1 ? t1.y : t1.x;
                const float top = v00 + wx * (v01 - v00);
                const float bot = v10 + wx * (v11 - v10);
                float v = top + wy * (bot - top);
                v = __builtin_amdgcn_fmed3f(v + bb, -1.0f, 1.0f);
                v = __builtin_amdgcn_fmed3f(v * cc, -1.0f, 1.0f);
                vals[c] = v;
            }
        }

        // ---- Saturation + cutout + store.
        const float gray = (vals[0] + vals[1] + vals[2]) * (1.0f / 3.0f);
        const int xpix = sx0 + (t << 4) + tx;
        const bool cut = ycut && (xpix >= cx0) && (xpix < cx0 + CUT_W);
        #pragma unroll
        for (int c = 0; c < Cn; ++c) {
            float v = gray + ss * (vals[c] - gray);
            v = __builtin_amdgcn_fmed3f(v, -1.0f, 1.0f);
            if (cut) v = __builtin_nontemporal_load(&noib[opix + c * PLANE]);
            __builtin_nontemporal_store(v, &outb[opix + c * PLANE]);
        }

        opix += 16;
        bx += step_x; by += step_y;
        xxt += step_x; yyt += step_y;
    }
}

extern "C" void kernel_launch(void* const* d_in, const int* in_sizes, int n_in,
                              void* d_out, int out_size, void* d_ws, size_t ws_size,
                              hipStream_t stream) {
    const float* images     = (const float*)d_in[0];
    const float* u_angle    = (const float*)d_in[1];
    const float* u_scale    = (const float*)d_in[2];
    const float* u_trans    = (const float*)d_in[3];
    const float* u_bright   = (const float*)d_in[4];
    const float* u_contrast = (const float*)d_in[5];
    const float* u_sat      = (const float*)d_in[6];
    const float* noise      = (const float*)d_in[7];
    const int*   m_flip     = (const int*)d_in[8];
    const int*   m_rot      = (const int*)d_in[9];
    const int*   m_scale    = (const int*)d_in[10];
    const int*   m_trans    = (const int*)d_in[11];
    const int*   m_bright   = (const int*)d_in[12];
    const int*   m_contrast = (const int*)d_in[13];
    const int*   m_sat      = (const int*)d_in[14];
    const int*   m_cut      = (const int*)d_in[15];
    const int*   y0p        = (const int*)d_in[16];
    const int*   x0p        = (const int*)d_in[17];
    float* out = (float*)d_out;

    dim3 block(16, 16);
    dim3 grid(Wn / (16 * NT), Hn / 16, Bn);   // (4, 32, 64) = 8192 blocks
    augment_kernel<<<grid, block, 0, stream>>>(
        images, u_angle, u_scale, u_trans, u_bright, u_contrast, u_sat, noise,
        m_flip, m_rot, m_scale, m_trans, m_bright, m_contrast, m_sat, m_cut,
        y0p, x0p, out);
}

// Round 7
// 509.512 us; speedup vs baseline: 1.0825x; 1.0162x over previous
//
#include <hip/hip_runtime.h>
#include <math.h>

// AugmentPipe: flip -> affine(rot/scale/trans) bilinear-reflect sample ->
// brightness -> contrast -> saturation -> cutout(noise). One fused pass.
// B=64, C=3, H=W=512, float32 in/out.
//
// R8 -> R9 (R8: 189us, VALU 28%, HBM 31%, conflicts 5%, occ 81% => nothing
// saturated; binder = staging-load latency exposed per tile by the
// load -> vmcnt(0) -> ds_write -> barrier convoy, ~500-900cy naked per tile).
//   (1) Register prefetch one tile ahead: loads for tile t+1 issue BEFORE
//       compute(t), ds_write consumes them after -> compute phase hides the
//       latency. Single 15.4KB LDS buffer kept -> 8 blocks/CU, VGPR ~40.
//   (2) Barriers = asm lgkmcnt(0) + s_barrier + sched_barrier(0): no vmcnt
//       drain (stores fly free; prefetch-reg readiness is enforced by the
//       compiler's own counted vmcnt before ds_write). Race-safe: both LDS
//       orders (reads-before-overwrite, writes-before-reads) are DS ops
//       covered by lgkmcnt(0)+barrier.
//   (3) R5-proven XCD swizzle back (R8 dropped it: FETCH 109->266MB).
//       8192 blocks % 8 == 0 -> bijective; 8 batches resident per XCD L2.
// Unchanged from R8: 128x16 strip (8 tiles), interior gate (reflect==clip,
// no clamps), FW=32 staging = exactly the written columns, FSTRIDE 40,
// fmed3 clamps, 32-bit saddr offsets, R2 fallback for edge tiles.

constexpr int Bn = 64;
constexpr int Cn = 3;
constexpr int Hn = 512;
constexpr int Wn = 512;
constexpr float TRANSLATE_STD = 0.125f;
constexpr float SCALE_STD = 0.2f;
constexpr int CUT_H = 256; // int(512*0.5)
constexpr int CUT_W = 256;

constexpr int FW = 32;        // staged box width == exactly what staging fills
constexpr int FSTRIDE = 40;   // LDS row stride (160B, 16B-aligned rows)
constexpr int FH_MAX = 32;    // staged rows capacity (math bound 30)
constexpr int CH_LDS = FSTRIDE * FH_MAX;   // 1280 floats per channel
constexpr int NT = 8;         // tiles per block (128x16 strip)
constexpr uint32_t PLANE = 512u * 512u;

typedef float f4v __attribute__((ext_vector_type(4)));
typedef float f2v __attribute__((ext_vector_type(2)));

__device__ __forceinline__ f2v load2(const float* p) {
    f2v r;
    __builtin_memcpy(&r, p, 8);
    return r;
}

__device__ __forceinline__ float reflect_coord(float v, float size) {
    v = fabsf(v + 0.5f);
    v = fmodf(v, 2.0f * size);
    v = fminf(v, 2.0f * size - v);
    return fminf(fmaxf(v - 0.5f, 0.0f), size - 1.0f);
}

// Barrier that drains DS ops only; VMEM (stores, prefetch loads) stays in
// flight across it.
__device__ __forceinline__ void pipe_barrier() {
    asm volatile("s_waitcnt lgkmcnt(0)" ::: "memory");
    __builtin_amdgcn_s_barrier();
    __builtin_amdgcn_sched_barrier(0);
}

__global__ __launch_bounds__(256) void augment_kernel(
    const float* __restrict__ images,
    const float* __restrict__ u_angle,
    const float* __restrict__ u_scale,
    const float* __restrict__ u_trans,
    const float* __restrict__ u_bright,
    const float* __restrict__ u_contrast,
    const float* __restrict__ u_sat,
    const float* __restrict__ noise,
    const int* __restrict__ m_flip,
    const int* __restrict__ m_rot,
    const int* __restrict__ m_scale,
    const int* __restrict__ m_trans,
    const int* __restrict__ m_bright,
    const int* __restrict__ m_contrast,
    const int* __restrict__ m_sat,
    const int* __restrict__ m_cut,
    const int* __restrict__ y0p,
    const int* __restrict__ x0p,
    float* __restrict__ out)
{
    __shared__ __align__(16) float lds[Cn * CH_LDS];   // 15360 B -> 8 blk/CU

    // XCD swizzle: linear dispatch id; each XCD (lin%8) gets a contiguous
    // 1024-block chunk = 8 whole batches, strip-then-row order inside.
    const int lin = blockIdx.x + (blockIdx.y << 2) + (blockIdx.z << 7);
    const int swz = ((lin & 7) << 10) + (lin >> 3);
    const int sx0 = (swz & 3) << 7;            // strip origin x (0..384)
    const int y16 = (swz >> 2) & 31;           // tile-row
    const int b   = swz >> 7;                  // batch

    const int tx  = threadIdx.x;               // 0..15
    const int ty  = threadIdx.y;               // 0..15
    const int y   = (y16 << 4) + ty;

    // ---- Per-batch setup (amortized over 8 tiles).
    const float angle = (m_rot[b] > 0) ? (u_angle[b] * 2.0f - 1.0f) * 3.14159265358979323846f : 0.0f;
    const float sc    = (m_scale[b] > 0) ? (u_scale[b] * 2.0f - 1.0f) * SCALE_STD + 1.0f : 1.0f;
    const float tr    = (m_trans[b] > 0) ? (u_trans[b] * 2.0f - 1.0f) * TRANSLATE_STD : 0.0f;
    const float bb    = (m_bright[b] > 0) ? u_bright[b] * 0.2f : 0.0f;
    const float cc    = (m_contrast[b] > 0) ? u_contrast[b] + 0.5f : 1.0f;
    const float ss    = (m_sat[b] > 0) ? u_sat[b] * 2.0f : 1.0f;
    const bool  flip  = m_flip[b] > 0;
    const bool  docut = m_cut[b] > 0;
    const int   cy0   = y0p[b];
    const int   cx0   = x0p[b];

    float saf, caf;
    __sincosf(angle, &saf, &caf);

    // Incremental affine basis (validated R6/R8).
    const float kk = sc * (512.0f / 511.0f);
    const float dxdx = caf * kk, dxdy = -saf * kk;
    const float dydx = saf * kk, dydy = caf * kk;
    const float xx_org = 256.0f * (sc * (saf - caf) + tr + 1.0f) - 0.5f;
    const float yy_org = 256.0f * (sc * (-saf - caf) + tr + 1.0f) - 0.5f;

    const float step_x = 16.0f * dxdx;
    const float step_y = 16.0f * dydx;

    float xxt = xx_org + (float)(sx0 + tx) * dxdx + (float)y * dxdy;
    float yyt = yy_org + (float)(sx0 + tx) * dydx + (float)y * dydy;

    const float fty = (float)(y16 << 4);
    float bx = xx_org + (float)sx0 * dxdx + fty * dxdy;   // rolling corner
    float by = yy_org + (float)sx0 * dydx + fty * dydy;
    const float sxx = 15.0f * dxdx, sxy = 15.0f * dxdy;
    const float syx = 15.0f * dydx, syy = 15.0f * dydy;
    const float min_dx = fminf(sxx, 0.0f) + fminf(sxy, 0.0f);
    const float max_dx = fmaxf(sxx, 0.0f) + fmaxf(sxy, 0.0f);
    const float min_dy = fminf(syx, 0.0f) + fminf(syy, 0.0f);
    const float max_dy = fmaxf(syx, 0.0f) + fmaxf(syy, 0.0f);

    const float* __restrict__ imgb = images + (size_t)b * (Cn * PLANE);
    float* __restrict__ outb       = out    + (size_t)b * (Cn * PLANE);
    const float* __restrict__ noib = noise  + (size_t)b * (Cn * PLANE);

    // Staging lane geometry: 32 rows x 8 quad-columns (= 32 cols = FW).
    const int tid = ty * 16 + tx;
    const int sr  = tid >> 3;            // staged row 0..31
    const int sq  = (tid & 7) << 2;      // quad col offset 0,4,..,28

    const bool ycut = docut && (y >= cy0) && (y < cy0 + CUT_H);
    uint32_t opix = (uint32_t)y * 512u + (uint32_t)(sx0 + tx);

    // ---- Box maker (interior gate: reflect==clip AND taps never clamp).
    int cx_lo, cy_lo, cfh; bool cok;
    int nx_lo, ny_lo, nfh; bool nok;
    auto mkbox = [&](float bxv, float byv, int& x_lo, int& y_lo, int& fh, bool& ok) {
        const float minxx = bxv + min_dx, maxxx = bxv + max_dx;
        const float minyy = byv + min_dy, maxyy = byv + max_dy;
        ok = (minxx >= 1.0f) && (maxxx <= 509.0f) &&
             (minyy >= 1.0f) && (maxyy <= 509.0f);
        x_lo = 0; y_lo = 0; fh = 0;
        if (ok) {
            x_lo = min(((int)minxx - 1) & ~3, Wn - FW);  // 4-aligned, <=480
            y_lo = (int)minyy - 1;
            fh   = ((int)maxyy + 2) - y_lo + 1;          // <= 30 by math
            if (fh > FH_MAX) ok = false;                 // safety
        }
    };

    // Prefetch registers (one tile's staged rows for this thread).
    f4v A{}, B{}, C{};
    auto loadR = [&](int x_lo, int y_lo) {
        const int scol = flip ? (508 - x_lo - sq) : (x_lo + sq);
        const uint32_t soff = (uint32_t)(y_lo + sr) * 512u + (uint32_t)scol;
        A = *(const f4v*)(imgb + soff);
        B = *(const f4v*)(imgb + soff + PLANE);
        C = *(const f4v*)(imgb + soff + 2 * PLANE);
    };
    auto writeR = [&]() {
        f4v a = A, b2 = B, c2 = C;
        if (flip) {
            a  = f4v{A.w, A.z, A.y, A.x};
            b2 = f4v{B.w, B.z, B.y, B.x};
            c2 = f4v{C.w, C.z, C.y, C.x};
        }
        float* d = &lds[sr * FSTRIDE + sq];
        *(f4v*)(d)              = a;
        *(f4v*)(d + CH_LDS)     = b2;
        *(f4v*)(d + 2 * CH_LDS) = c2;
    };

    // ---- Prologue: tile0 staged; tile1 loads in flight.
    mkbox(bx, by, cx_lo, cy_lo, cfh, cok);
    if (cok && sr < cfh) { loadR(cx_lo, cy_lo); writeR(); }  // auto vmcnt
    bx += step_x; by += step_y;
    mkbox(bx, by, nx_lo, ny_lo, nfh, nok);
    if (nok && sr < nfh) loadR(nx_lo, ny_lo);
    pipe_barrier();                           // publish tile0

    #pragma unroll 1
    for (int t = 0; t < NT; ++t) {
        float vals[Cn];
        if (cok) {
            // ---- Exact bilinear from LDS: no clamps, no selects.
            const float fx = xxt - (float)cx_lo;
            const float fy = yyt - (float)cy_lo;
            const int xi = (int)fx;
            const int yi = (int)fy;
            const float wx = fx - (float)xi;
            const float wy = fy - (float)yi;
            const float* ph = &lds[yi * FSTRIDE + xi];
            #pragma unroll
            for (int c = 0; c < Cn; ++c) {
                const float v00 = ph[0], v01 = ph[1];
                const float v10 = ph[FSTRIDE], v11 = ph[FSTRIDE + 1];
                ph += CH_LDS;
                const float top = v00 + wx * (v01 - v00);
                const float bot = v10 + wx * (v11 - v10);
                float v = top + wy * (bot - top);
                v = __builtin_amdgcn_fmed3f(v + bb, -1.0f, 1.0f);  // bright
                v = __builtin_amdgcn_fmed3f(v * cc, -1.0f, 1.0f);  // contrast
                vals[c] = v;
            }
        } else {
            // ---- Edge/reflecting tiles: direct global gather, true reflect.
            const float rxx = reflect_coord(xxt, (float)Wn);
            const float ryy = reflect_coord(yyt, (float)Hn);
            const float x0f = floorf(rxx);
            const float y0f = floorf(ryy);
            const float wx = rxx - x0f;
            const float wy = ryy - y0f;
            int x0i = (int)fminf(fmaxf(x0f, 0.0f), 511.0f);
            int x1i = (int)fminf(x0f + 1.0f, 511.0f);
            const int y0i = (int)fminf(fmaxf(y0f, 0.0f), 511.0f);
            const int y1i = (int)fminf(y0f + 1.0f, 511.0f);
            if (flip) { x0i = 511 - x0i; x1i = 511 - x1i; }
            const int xbase = min(min(x0i, x1i), 510);
            const bool s0 = (x0i != xbase);
            const bool s1 = (x1i != xbase);
            const uint32_t r0 = (uint32_t)(y0i * 512 + xbase);
            const uint32_t r1 = (uint32_t)(y1i * 512 + xbase);
            #pragma unroll
            for (int c = 0; c < Cn; ++c) {
                const f2v t0 = load2(imgb + r0 + c * PLANE);
                const f2v t1 = load2(imgb + r1 + c * PLANE);
                const float v00 = s0 ? t0.y : t0.x;
                const float v01 = s1 ? t0.y : t0.x;
                const float v10 = s0 ? t1.y : t1.x;
                const float v11 = s1 ? t1.y : t1.x;
                const float top = v00 + wx * (v01 - v00);
                const float bot = v10 + wx * (v11 - v10);
                float v = top + wy * (bot - top);
                v = __builtin_amdgcn_fmed3f(v + bb, -1.0f, 1.0f);
                v = __builtin_amdgcn_fmed3f(v * cc, -1.0f, 1.0f);
                vals[c] = v;
            }
        }

        // ---- Saturation + cutout + store (stores fly across barriers).
        const float gray = (vals[0] + vals[1] + vals[2]) * (1.0f / 3.0f);
        const int xpix = sx0 + (t << 4) + tx;
        const bool cut = ycut && (xpix >= cx0) && (xpix < cx0 + CUT_W);
        #pragma unroll
        for (int c = 0; c < Cn; ++c) {
            float v = gray + ss * (vals[c] - gray);
            v = __builtin_amdgcn_fmed3f(v, -1.0f, 1.0f);
            if (cut) v = __builtin_nontemporal_load(&noib[opix + c * PLANE]);
            __builtin_nontemporal_store(v, &outb[opix + c * PLANE]);
        }
        opix += 16;
        xxt += step_x; yyt += step_y;

        if (t == NT - 1) break;

        pipe_barrier();                       // all reads of tile t done
        cx_lo = nx_lo; cy_lo = ny_lo; cfh = nfh; cok = nok;
        if (cok && sr < cfh) writeR();        // counted-vmcnt wait on A,B,C
        bx += step_x; by += step_y;
        if (t + 2 < NT) {
            mkbox(bx, by, nx_lo, ny_lo, nfh, nok);
            if (nok && sr < nfh) loadR(nx_lo, ny_lo);   // covers next phase
        } else {
            nok = false;
        }
        pipe_barrier();                       // publish tile t+1
    }
}

extern "C" void kernel_launch(void* const* d_in, const int* in_sizes, int n_in,
                              void* d_out, int out_size, void* d_ws, size_t ws_size,
                              hipStream_t stream) {
    const float* images     = (const float*)d_in[0];
    const float* u_angle    = (const float*)d_in[1];
    const float* u_scale    = (const float*)d_in[2];
    const float* u_trans    = (const float*)d_in[3];
    const float* u_bright   = (const float*)d_in[4];
    const float* u_contrast = (const float*)d_in[5];
    const float* u_sat      = (const float*)d_in[6];
    const float* noise      = (const float*)d_in[7];
    const int*   m_flip     = (const int*)d_in[8];
    const int*   m_rot      = (const int*)d_in[9];
    const int*   m_scale    = (const int*)d_in[10];
    const int*   m_trans    = (const int*)d_in[11];
    const int*   m_bright   = (const int*)d_in[12];
    const int*   m_contrast = (const int*)d_in[13];
    const int*   m_sat      = (const int*)d_in[14];
    const int*   m_cut      = (const int*)d_in[15];
    const int*   y0p        = (const int*)d_in[16];
    const int*   x0p        = (const int*)d_in[17];
    float* out = (float*)d_out;

    dim3 block(16, 16);
    dim3 grid(Wn / (16 * NT), Hn / 16, Bn);   // (4, 32, 64) = 8192 blocks
    augment_kernel<<<grid, block, 0, stream>>>(
        images, u_angle, u_scale, u_trans, u_bright, u_contrast, u_sat, noise,
        m_flip, m_rot, m_scale, m_trans, m_bright, m_contrast, m_sat, m_cut,
        y0p, x0p, out);
}